// Round 8
// baseline (4464.254 us; speedup 1.0000x reference)
//
#include <hip/hip_runtime.h>
#include <math.h>

// ---------------------------------------------------------------------------
// SpatialGNN: 3x GCN (residual) + 4-head GAT + MLP + log_softmax
// N=100000, E=1600000, IN=8, HID=64, HEADS=4, OUT=3
//
// R7 changes vs R6:
//  - CSR scatter was 127us with 105MB WRITE for 6.4MB payload (cross-XCD
//    partial-line writeback amplification). Now: bucket edges by dst-range
//    (<=7 contiguous buckets) with ballot-aggregated append, then scatter
//    with bucket = blockIdx%8 (matches round-robin block->XCD) so each
//    bucket's col_src range stays in ONE XCD's L2 -> lines merge.
//  - agg buffer fp16: gat_agg->mlp round-trip 204MB -> 102MB.
// ---------------------------------------------------------------------------

typedef _Float16 half8 __attribute__((ext_vector_type(8)));
typedef _Float16 half2v __attribute__((ext_vector_type(2)));

__device__ __forceinline__ float leaky02(float v) { return v > 0.f ? v : 0.2f * v; }

// ---- cross-lane reduction helpers (DPP/swizzle; minimize DS-pipe ops) -----

template <int CTRL>
__device__ __forceinline__ float dpp_add(float v) {
    int iv = __builtin_bit_cast(int, v);
    int r = __builtin_amdgcn_update_dpp(iv, iv, CTRL, 0xF, 0xF, false);
    return v + __builtin_bit_cast(float, r);
}
template <int OFF>
__device__ __forceinline__ float swz_add(float v) {
    int r = __builtin_amdgcn_ds_swizzle(__builtin_bit_cast(int, v), OFF);
    return v + __builtin_bit_cast(float, r);
}
__device__ __forceinline__ float red8(float v) {
    v = dpp_add<0xB1>(v);     // xor1
    v = dpp_add<0x4E>(v);     // xor2
    v = swz_add<0x101F>(v);   // xor4
    return v;
}
__device__ __forceinline__ float red64(float v) {
    v = dpp_add<0xB1>(v);
    v = dpp_add<0x4E>(v);
    v = swz_add<0x101F>(v);
    v = dpp_add<0x128>(v);    // xor8: row_ror:8
    v = swz_add<0x401F>(v);   // xor16
    v = v + __shfl_xor(v, 32);
    return v;
}
__device__ __forceinline__ float sel4(int g, float v0, float v1, float v2, float v3) {
    return g == 0 ? v0 : g == 1 ? v1 : g == 2 ? v2 : v3;
}

// ---- CSR build ------------------------------------------------------------

// counts per node + per-bucket edge counts (wave-aggregated atomics)
__global__ void count_kernel(const int* __restrict__ dst, int E, int shift, int nbuck,
                             int* __restrict__ counts, int* __restrict__ bcnt) {
    int e = blockIdx.x * blockDim.x + threadIdx.x;
    int lane = threadIdx.x & 63;
    int k = -1;
    if (e < E) {
        int d = dst[e];
        atomicAdd(&counts[d], 1);
        k = d >> shift;
    }
    for (int kk = 0; kk < nbuck; ++kk) {
        unsigned long long m = __ballot(k == kk);
        if (m == 0) continue;
        int leader = __builtin_ctzll(m);
        if (lane == leader) atomicAdd(&bcnt[kk], (int)__builtin_popcountll(m));
    }
}

__global__ void scan_pass1(const int* __restrict__ counts, int n, int* __restrict__ blockSums) {
    __shared__ int sh[256];
    int base = blockIdx.x * 2048;
    int tid = threadIdx.x;
    int s = 0;
#pragma unroll
    for (int j = 0; j < 8; ++j) {
        int idx = base + tid * 8 + j;
        if (idx < n) s += counts[idx];
    }
    sh[tid] = s;
    __syncthreads();
    for (int off = 128; off > 0; off >>= 1) {
        if (tid < off) sh[tid] += sh[tid + off];
        __syncthreads();
    }
    if (tid == 0) blockSums[blockIdx.x] = sh[0];
}

__global__ void scan_pass2(const int* __restrict__ blockSums, int nb, int* __restrict__ blockOffs,
                           const int* __restrict__ bcnt, int nbuck,
                           int* __restrict__ boff, int* __restrict__ bcur) {
    if (threadIdx.x == 0 && blockIdx.x == 0) {
        int run = 0;
        for (int i = 0; i < nb; ++i) { blockOffs[i] = run; run += blockSums[i]; }
        int r2 = 0;
        for (int k = 0; k < nbuck; ++k) { boff[k] = r2; bcur[k] = r2; r2 += bcnt[k]; }
        boff[nbuck] = r2;
    }
}

__global__ void scan_pass3(const int* __restrict__ counts, int n,
                           const int* __restrict__ blockOffs,
                           const float* __restrict__ x,
                           int* __restrict__ row_ptr, int* __restrict__ cursor,
                           float* __restrict__ dinv, float* __restrict__ rdinv,
                           _Float16* __restrict__ xs) {
    __shared__ int sh[256];
    int base = blockIdx.x * 2048;
    int tid = threadIdx.x;
    int cnt[8];
    int local = 0;
#pragma unroll
    for (int j = 0; j < 8; ++j) {
        int idx = base + tid * 8 + j;
        cnt[j] = (idx < n) ? counts[idx] : 0;
        local += cnt[j];
    }
    sh[tid] = local;
    __syncthreads();
    for (int off = 1; off < 256; off <<= 1) {
        int v = (tid >= off) ? sh[tid - off] : 0;
        __syncthreads();
        sh[tid] += v;
        __syncthreads();
    }
    int run = blockOffs[blockIdx.x] + sh[tid] - local;
#pragma unroll
    for (int j = 0; j < 8; ++j) {
        int idx = base + tid * 8 + j;
        if (idx < n) {
            row_ptr[idx] = run;
            cursor[idx] = run;
            float dv = rsqrtf((float)(cnt[j] + 1));
            dinv[idx] = dv;
            rdinv[idx] = sqrtf((float)(cnt[j] + 1));
#pragma unroll
            for (int t = 0; t < 8; ++t) xs[idx * 8 + t] = (_Float16)(dv * x[idx * 8 + t]);
            run += cnt[j];
            if (idx == n - 1) row_ptr[n] = run;
        }
    }
}

// phase A: append (src,dst) pairs into per-bucket streams (coalesced-ish)
__global__ void bucket_kernel(const int* __restrict__ src, const int* __restrict__ dst, int E,
                              int shift, int nbuck,
                              int* __restrict__ bcur, int2* __restrict__ pairs) {
    int e = blockIdx.x * blockDim.x + threadIdx.x;
    int lane = threadIdx.x & 63;
    int s = 0, d = 0, k = -1;
    if (e < E) { s = src[e]; d = dst[e]; k = d >> shift; }
    for (int kk = 0; kk < nbuck; ++kk) {
        unsigned long long m = __ballot(k == kk);
        if (m == 0) continue;
        int leader = __builtin_ctzll(m);
        int base = 0;
        if (lane == leader) base = atomicAdd(&bcur[kk], (int)__builtin_popcountll(m));
        base = __shfl(base, leader);
        if (k == kk) {
            int rank = __builtin_popcountll(m & ((1ULL << lane) - 1ULL));
            pairs[base + rank] = make_int2(s, d);
        }
    }
}

// phase B: scatter within bucket blockIdx%8 (-> XCD-local col_src writes)
__global__ void scatter_kernel(const int2* __restrict__ pairs, const int* __restrict__ boff,
                               int nbuck,
                               int* __restrict__ cursor, int* __restrict__ col_src) {
    int k = blockIdx.x & 7;
    if (k >= nbuck) return;
    int bstart = boff[k], bend = boff[k + 1];
    int nblk = gridDim.x >> 3;
    int c = blockIdx.x >> 3;
    for (int i = bstart + c * blockDim.x + threadIdx.x; i < bend; i += nblk * blockDim.x) {
        int2 p = pairs[i];
        int pos = atomicAdd(&cursor[p.y], 1);
        col_src[pos] = p.x;
    }
}

// ---- weight precompute: Ccomb/bcomb + attention-effective vectors ---------

__global__ void ccomb_kernel(const float* __restrict__ Wg, const float* __restrict__ bg,
                             const float* __restrict__ wc1, const float* __restrict__ bc1,
                             const float* __restrict__ att_src, const float* __restrict__ att_dst,
                             float* __restrict__ Ccomb, float* __restrict__ bcomb,
                             float* __restrict__ wse, float* __restrict__ wde) {
    int bid = blockIdx.x;   // 0..256
    int j = threadIdx.x;    // 64 threads
    if (bid < 256) {
        int h = bid >> 6, k = bid & 63;
        float s = 0.f;
        for (int c = 0; c < 64; ++c)
            s += Wg[k * 256 + h * 64 + c] * wc1[(h * 64 + c) * 64 + j];
        Ccomb[bid * 64 + j] = s;
    } else {
        float s = bc1[j];
        for (int i = 0; i < 256; ++i) s += bg[i] * wc1[i * 64 + j];
        bcomb[j] = s;
#pragma unroll
        for (int h = 0; h < 4; ++h) {
            float ss = 0.f, sd = 0.f;
            for (int c = 0; c < 64; ++c) {
                float w = Wg[j * 256 + h * 64 + c];
                ss += w * att_src[h * 64 + c];
                sd += w * att_dst[h * 64 + c];
            }
            wse[j * 4 + h] = ss;
            wde[j * 4 + h] = sd;
        }
    }
}

// ---- GCN layer 1: one edge per lane (16B half8 row) -----------------------

__global__ void gcn_layer1(const half8* __restrict__ xs8,
                           const float* __restrict__ W1, const float* __restrict__ b1,
                           const int* __restrict__ row_ptr, const int* __restrict__ col_src,
                           const float* __restrict__ dinv, int n,
                           _Float16* __restrict__ hs1) {
    int tid = threadIdx.x, lane = tid & 63, wid = tid >> 6;
    int node = blockIdx.x * 4 + wid;
    if (node >= n) return;
    int beg = row_ptr[node], end = row_ptr[node + 1];
    int deg = end - beg;
    float acc[8] = {0.f, 0.f, 0.f, 0.f, 0.f, 0.f, 0.f, 0.f};
    for (int base = 0; base < deg; base += 64) {
        int cs = col_src[min(beg + base + lane, end - 1)];
        half8 v = xs8[cs];
        if (base + lane < deg) {
#pragma unroll
            for (int c = 0; c < 8; ++c) acc[c] += (float)v[c];
        }
    }
#pragma unroll
    for (int c = 0; c < 8; ++c) acc[c] = red64(acc[c]);
    half8 sv = xs8[node];
    float di = dinv[node];
    float agg[8];
#pragma unroll
    for (int c = 0; c < 8; ++c) agg[c] = (acc[c] + (float)sv[c]) * di;
    float sum = b1[lane];
#pragma unroll
    for (int k = 0; k < 8; ++k) sum = fmaf(agg[k], W1[k * 64 + lane], sum);
    hs1[node * 64 + lane] = (_Float16)(di * fmaxf(sum, 0.f));
}

// ---- GCN layer 2/3: g=lane&7 edge slots, t=lane>>3 channel chunks ---------

template <bool LAST>
__global__ void gcn_layer64(const _Float16* __restrict__ hs_in,
                            const float* __restrict__ W, const float* __restrict__ b,
                            const int* __restrict__ row_ptr, const int* __restrict__ col_src,
                            const float* __restrict__ dinv, const float* __restrict__ rdinv,
                            const float* __restrict__ wse, const float* __restrict__ wde,
                            int n,
                            _Float16* __restrict__ hout,
                            float4* __restrict__ a_src4, float4* __restrict__ a_dst4) {
    __shared__ float agg_lds[4][64];
    int tid = threadIdx.x;
    int lane = tid & 63;
    int wid = tid >> 6;
    int t = lane >> 3, g = lane & 7;
    const half8* hs8 = (const half8*)hs_in;
    float wreg[64];
#pragma unroll
    for (int k = 0; k < 64; ++k) wreg[k] = W[k * 64 + lane];
    float bl = b[lane];
    float4 we, wd;
    if (LAST) {
        we = ((const float4*)wse)[lane];
        wd = ((const float4*)wde)[lane];
    }
    int nw = gridDim.x * 4;
    for (int node = blockIdx.x * 4 + wid; node < n; node += nw) {
        int beg = row_ptr[node], end = row_ptr[node + 1];
        int deg = end - beg;
        half8 sv = hs8[node * 8 + t];
        float ac[8];
#pragma unroll
        for (int c = 0; c < 8; ++c) ac[c] = (g == 0) ? (float)sv[c] : 0.f;
        for (int base = 0; base < deg; base += 64) {
            int cs = col_src[min(beg + base + lane, end - 1)];
            int lim = min(deg - base, 64);
            for (int chunk = 0; chunk < lim; chunk += 16) {
#pragma unroll
                for (int u = 0; u < 2; ++u) {
                    int eo = chunk + u * 8 + g;
                    int s = __shfl(cs, eo);
                    half8 v = hs8[s * 8 + t];
                    if (eo < lim) {
#pragma unroll
                        for (int c = 0; c < 8; ++c) ac[c] += (float)v[c];
                    }
                }
            }
        }
        float di = dinv[node];
#pragma unroll
        for (int c = 0; c < 8; ++c) ac[c] = red8(ac[c]) * di;
        if (g == 0) {
            *(float4*)&agg_lds[wid][t * 8]     = make_float4(ac[0], ac[1], ac[2], ac[3]);
            *(float4*)&agg_lds[wid][t * 8 + 4] = make_float4(ac[4], ac[5], ac[6], ac[7]);
        }
        __asm__ volatile("s_waitcnt lgkmcnt(0)" ::: "memory");
        float sum = bl;
#pragma unroll
        for (int k4 = 0; k4 < 16; ++k4) {
            float4 a4 = *(const float4*)&agg_lds[wid][k4 * 4];
            sum = fmaf(a4.x, wreg[k4 * 4 + 0], sum);
            sum = fmaf(a4.y, wreg[k4 * 4 + 1], sum);
            sum = fmaf(a4.z, wreg[k4 * 4 + 2], sum);
            sum = fmaf(a4.w, wreg[k4 * 4 + 3], sum);
        }
        float hprev = rdinv[node] * (float)hs_in[node * 64 + lane];
        float hv = hprev + fmaxf(sum, 0.f);
        if (!LAST) {
            hout[node * 64 + lane] = (_Float16)(di * hv);
        } else {
            hout[node * 64 + lane] = (_Float16)hv;
            float vs0 = red64(hv * we.x), vs1 = red64(hv * we.y);
            float vs2 = red64(hv * we.z), vs3 = red64(hv * we.w);
            float vd0 = red64(hv * wd.x), vd1 = red64(hv * wd.y);
            float vd2 = red64(hv * wd.z), vd3 = red64(hv * wd.w);
            if (lane == 0) {
                a_src4[node] = make_float4(vs0, vs1, vs2, vs3);
                a_dst4[node] = make_float4(vd0, vd1, vd2, vd3);
            }
        }
    }
}

// ---- GAT aggregate: writes fp16 agg rows ----------------------------------

__global__ void gat_agg(const _Float16* __restrict__ h3,
                        const float4* __restrict__ a_src4, const float4* __restrict__ a_dst4,
                        const int* __restrict__ row_ptr, const int* __restrict__ col_src,
                        int nbase, int ncount, _Float16* __restrict__ aggout) {
    int tid = threadIdx.x, lane = tid & 63, wid = tid >> 6;
    int li = blockIdx.x * 4 + wid;
    if (li >= ncount) return;
    int node = nbase + li;
    int t = lane >> 3, g = lane & 7;
    const half8* h38 = (const half8*)h3;

    float4 ad = a_dst4[node];
    float4 asf = a_src4[node];
    half8 hself = h38[node * 8 + t];
    float A[4][8], dh[4];
    {
        float w0 = __expf(leaky02(asf.x + ad.x));
        float w1 = __expf(leaky02(asf.y + ad.y));
        float w2 = __expf(leaky02(asf.z + ad.z));
        float w3 = __expf(leaky02(asf.w + ad.w));
        float m0 = (g == 0) ? 1.f : 0.f;
        dh[0] = m0 * w0; dh[1] = m0 * w1; dh[2] = m0 * w2; dh[3] = m0 * w3;
#pragma unroll
        for (int c = 0; c < 8; ++c) {
            float hvc = (float)hself[c];
            A[0][c] = dh[0] * hvc;
            A[1][c] = dh[1] * hvc;
            A[2][c] = dh[2] * hvc;
            A[3][c] = dh[3] * hvc;
        }
    }
    int beg = row_ptr[node], end = row_ptr[node + 1];
    int deg = end - beg;
    for (int base = 0; base < deg; base += 64) {
        int cs = col_src[min(beg + base + lane, end - 1)];
        int lim = min(deg - base, 64);
        for (int chunk = 0; chunk < lim; chunk += 16) {
#pragma unroll
            for (int u = 0; u < 2; ++u) {
                int eo = chunk + u * 8 + g;
                int s = __shfl(cs, eo);
                float4 as = a_src4[s];
                half8 hv = h38[s * 8 + t];
                float valid = (eo < lim) ? 1.f : 0.f;
                float w0 = valid * __expf(leaky02(as.x + ad.x));
                float w1 = valid * __expf(leaky02(as.y + ad.y));
                float w2 = valid * __expf(leaky02(as.z + ad.z));
                float w3 = valid * __expf(leaky02(as.w + ad.w));
#pragma unroll
                for (int c = 0; c < 8; ++c) {
                    float hvc = (float)hv[c];
                    A[0][c] = fmaf(w0, hvc, A[0][c]);
                    A[1][c] = fmaf(w1, hvc, A[1][c]);
                    A[2][c] = fmaf(w2, hvc, A[2][c]);
                    A[3][c] = fmaf(w3, hvc, A[3][c]);
                }
                dh[0] += w0; dh[1] += w1; dh[2] += w2; dh[3] += w3;
            }
        }
    }
#pragma unroll
    for (int h = 0; h < 4; ++h) {
#pragma unroll
        for (int c = 0; c < 8; ++c) A[h][c] = red8(A[h][c]);
        dh[h] = red8(dh[h]);
    }
    float r0 = 1.f / (dh[0] + 1e-16f);
    float r1 = 1.f / (dh[1] + 1e-16f);
    float r2 = 1.f / (dh[2] + 1e-16f);
    float r3 = 1.f / (dh[3] + 1e-16f);
    if (g < 4) {
        float r = sel4(g, r0, r1, r2, r3);
        half8 hv;
#pragma unroll
        for (int c = 0; c < 8; ++c)
            hv[c] = (_Float16)(sel4(g, A[0][c], A[1][c], A[2][c], A[3][c]) * r);
        *(half8*)(aggout + (size_t)li * 256 + g * 64 + t * 8) = hv;
    }
}

// ---- MLP: Ccomb rows in VGPRs (4-wave split), fp16 agg scalar loads -------

__global__ __launch_bounds__(256) void mlp_kernel(
        const _Float16* __restrict__ agg,
        const float* __restrict__ Ccomb, const float* __restrict__ bcomb,
        const float* __restrict__ wc2, const float* __restrict__ bc2,
        int nbase, int ncount, float* __restrict__ out) {
    __shared__ float part[4][4][64];   // [node-in-chunk][wave][lane]
    int tid = threadIdx.x;
    int lane = tid & 63;
    int w = __builtin_amdgcn_readfirstlane(tid >> 6);
    float creg[64];
#pragma unroll
    for (int i = 0; i < 64; ++i) creg[i] = Ccomb[(w * 64 + i) * 64 + lane];
    float bz = bcomb[lane];
    float w20 = wc2[lane * 3 + 0], w21 = wc2[lane * 3 + 1], w22 = wc2[lane * 3 + 2];
    float bb0 = bc2[0], bb1 = bc2[1], bb2 = bc2[2];
    int nchunks = (ncount + 3) >> 2;
    for (int ch = blockIdx.x; ch < nchunks; ch += gridDim.x) {
        int base = ch * 4;
#pragma unroll
        for (int j = 0; j < 4; ++j) {
            int li = min(base + j, ncount - 1);
            const half2v* a2 = (const half2v*)(agg + (size_t)li * 256 + w * 64);
            float p = 0.f;
#pragma unroll
            for (int i = 0; i < 32; ++i) {
                half2v hv = a2[i];
                p = fmaf((float)hv[0], creg[2 * i], p);
                p = fmaf((float)hv[1], creg[2 * i + 1], p);
            }
            part[j][w][lane] = p;
        }
        __syncthreads();
        int li = base + w;
        if (li < ncount) {
            float z = bz + part[w][0][lane] + part[w][1][lane]
                         + part[w][2][lane] + part[w][3][lane];
            z = fmaxf(z, 0.f);
            float p0 = red64(z * w20);
            float p1 = red64(z * w21);
            float p2 = red64(z * w22);
            if (lane == 0) {
                float e0 = p0 + bb0, e1 = p1 + bb1, e2 = p2 + bb2;
                float mx = fmaxf(e0, fmaxf(e1, e2));
                float lse = mx + logf(expf(e0 - mx) + expf(e1 - mx) + expf(e2 - mx));
                int nn = nbase + li;
                out[nn * 3 + 0] = e0 - lse;
                out[nn * 3 + 1] = e1 - lse;
                out[nn * 3 + 2] = e2 - lse;
            }
        }
        __syncthreads();
    }
}

// ---------------------------------------------------------------------------

extern "C" void kernel_launch(void* const* d_in, const int* in_sizes, int n_in,
                              void* d_out, int out_size, void* d_ws, size_t ws_size,
                              hipStream_t stream) {
    const float* x       = (const float*)d_in[0];
    const int*   ei      = (const int*)d_in[1];
    const float* w1      = (const float*)d_in[2];
    const float* b1      = (const float*)d_in[3];
    const float* w2      = (const float*)d_in[4];
    const float* b2      = (const float*)d_in[5];
    const float* w3      = (const float*)d_in[6];
    const float* b3      = (const float*)d_in[7];
    const float* wg      = (const float*)d_in[8];
    const float* bg      = (const float*)d_in[9];
    const float* att_s   = (const float*)d_in[10];
    const float* att_d   = (const float*)d_in[11];
    const float* wc1     = (const float*)d_in[12];
    const float* bc1     = (const float*)d_in[13];
    const float* wc2     = (const float*)d_in[14];
    const float* bc2     = (const float*)d_in[15];
    float* out = (float*)d_out;

    const int N = in_sizes[0] / 8;
    const int E = in_sizes[1] / 2;
    const int* srcv = ei;
    const int* dstv = ei + E;

    // bucket shift: <=7 buckets of contiguous dst ranges
    int shift = 0;
    while (((N - 1) >> shift) > 6) ++shift;
    int nbuck = ((N - 1) >> shift) + 1;

    char* ws = (char*)d_ws;
    size_t off = 0;
    auto alloc = [&](size_t bytes) -> char* {
        char* p = ws + off;
        off += (bytes + 255) & ~(size_t)255;
        return p;
    };
    int*      counts    = (int*)alloc((size_t)N * 4);
    int*      row_ptr   = (int*)alloc((size_t)(N + 1) * 4);
    int*      cursor    = (int*)alloc((size_t)N * 4);
    int*      col_src   = (int*)alloc((size_t)E * 4);
    int2*     pairs     = (int2*)alloc((size_t)E * 8);
    int*      blockSums = (int*)alloc(4096 * 4);
    int*      blockOffs = (int*)alloc(4096 * 4);
    int*      bcnt      = (int*)alloc(16 * 4);
    int*      boff      = (int*)alloc(16 * 4);
    int*      bcur      = (int*)alloc(16 * 4);
    float*    dinv      = (float*)alloc((size_t)N * 4);
    float*    rdinv     = (float*)alloc((size_t)N * 4);
    _Float16* xs        = (_Float16*)alloc((size_t)N * 8 * 2);
    float*    a_src     = (float*)alloc((size_t)N * 16);
    float*    a_dst     = (float*)alloc((size_t)N * 16);
    float*    wse       = (float*)alloc(256 * 4);
    float*    wde       = (float*)alloc(256 * 4);
    float*    Ccomb     = (float*)alloc(256 * 64 * 4);
    float*    bcomb     = (float*)alloc(64 * 4);
    _Float16* bufA      = (_Float16*)alloc((size_t)N * 64 * 2);  // hs1, later h3
    _Float16* bufB      = (_Float16*)alloc((size_t)N * 64 * 2);  // hs2
    const int S = (N + 3) / 4;                                   // stripe size
    _Float16* aggbuf    = (_Float16*)alloc((size_t)S * 256 * 2);
    _Float16* hs1 = bufA;
    _Float16* hs2 = bufB;
    _Float16* h3  = bufA;   // hs1 dead once layer3 runs
    (void)ws_size; (void)n_in; (void)out_size;

    hipMemsetAsync(counts, 0, (size_t)N * 4, stream);
    hipMemsetAsync(bcnt, 0, 16 * 4, stream);

    const int TPB = 256;
    int gridE = (E + TPB - 1) / TPB;
    count_kernel<<<gridE, TPB, 0, stream>>>(dstv, E, shift, nbuck, counts, bcnt);

    int NB = (N + 2047) / 2048;
    scan_pass1<<<NB, TPB, 0, stream>>>(counts, N, blockSums);
    scan_pass2<<<1, 64, 0, stream>>>(blockSums, NB, blockOffs, bcnt, nbuck, boff, bcur);
    scan_pass3<<<NB, TPB, 0, stream>>>(counts, N, blockOffs, x,
                                       row_ptr, cursor, dinv, rdinv, xs);
    bucket_kernel<<<gridE, TPB, 0, stream>>>(srcv, dstv, E, shift, nbuck, bcur, pairs);
    scatter_kernel<<<1024, TPB, 0, stream>>>(pairs, boff, nbuck, cursor, col_src);

    ccomb_kernel<<<257, 64, 0, stream>>>(wg, bg, wc1, bc1, att_s, att_d,
                                         Ccomb, bcomb, wse, wde);

    int gridN = (N + 3) / 4;
    gcn_layer1<<<gridN, TPB, 0, stream>>>((const half8*)xs, w1, b1, row_ptr, col_src,
                                          dinv, N, hs1);
    const int G64 = 1024;   // grid-stride: ~24 nodes/wave, amortizes W VGPR load
    gcn_layer64<false><<<G64, TPB, 0, stream>>>(hs1, w2, b2, row_ptr, col_src,
                                                dinv, rdinv, wse, wde, N, hs2,
                                                nullptr, nullptr);
    gcn_layer64<true><<<G64, TPB, 0, stream>>>(hs2, w3, b3, row_ptr, col_src,
                                               dinv, rdinv, wse, wde, N, h3,
                                               (float4*)a_src, (float4*)a_dst);

    // GAT + MLP in 4 stripes reusing the agg slab
    for (int s = 0; s < 4; ++s) {
        int nbase = s * S;
        if (nbase >= N) break;
        int ncount = min(S, N - nbase);
        int gridA = (ncount + 3) / 4;   // 1 node per wave
        gat_agg<<<gridA, TPB, 0, stream>>>(h3, (const float4*)a_src, (const float4*)a_dst,
                                           row_ptr, col_src, nbase, ncount, aggbuf);
        mlp_kernel<<<512, TPB, 0, stream>>>(aggbuf, Ccomb, bcomb, wc2, bc2,
                                            nbase, ncount, out);
    }
}

// Round 9
// 709.690 us; speedup vs baseline: 6.2904x; 6.2904x over previous
//
#include <hip/hip_runtime.h>
#include <math.h>

// ---------------------------------------------------------------------------
// SpatialGNN: 3x GCN (residual) + 4-head GAT + MLP + log_softmax
// N=100000, E=1600000, IN=8, HID=64, HEADS=4, OUT=3
//
// R9 changes vs R8 (R8's bucket append serialized on 7 global atomic lines,
// 1894us — reverted):
//  - scatter: multi-pass range-filtered. Block group blockIdx&7 (~XCD) scans
//    the whole edge list and scatters only dsts in its contiguous 1/8 node
//    range -> col_src/cursor writes stay XCD-local, lines merge in one L2.
//    Extra coalesced re-reads (~102MB) are cheap vs 105MB write amplification.
//  - count_kernel / scan_pass2 reverted to simple R7 forms.
//  - keeps R8's fp16 agg buffer + fp16 mlp loads.
// ---------------------------------------------------------------------------

typedef _Float16 half8 __attribute__((ext_vector_type(8)));
typedef _Float16 half2v __attribute__((ext_vector_type(2)));

__device__ __forceinline__ float leaky02(float v) { return v > 0.f ? v : 0.2f * v; }

// ---- cross-lane reduction helpers (DPP/swizzle; minimize DS-pipe ops) -----

template <int CTRL>
__device__ __forceinline__ float dpp_add(float v) {
    int iv = __builtin_bit_cast(int, v);
    int r = __builtin_amdgcn_update_dpp(iv, iv, CTRL, 0xF, 0xF, false);
    return v + __builtin_bit_cast(float, r);
}
template <int OFF>
__device__ __forceinline__ float swz_add(float v) {
    int r = __builtin_amdgcn_ds_swizzle(__builtin_bit_cast(int, v), OFF);
    return v + __builtin_bit_cast(float, r);
}
__device__ __forceinline__ float red8(float v) {
    v = dpp_add<0xB1>(v);     // xor1
    v = dpp_add<0x4E>(v);     // xor2
    v = swz_add<0x101F>(v);   // xor4
    return v;
}
__device__ __forceinline__ float red64(float v) {
    v = dpp_add<0xB1>(v);
    v = dpp_add<0x4E>(v);
    v = swz_add<0x101F>(v);
    v = dpp_add<0x128>(v);    // xor8: row_ror:8
    v = swz_add<0x401F>(v);   // xor16
    v = v + __shfl_xor(v, 32);
    return v;
}
__device__ __forceinline__ float sel4(int g, float v0, float v1, float v2, float v3) {
    return g == 0 ? v0 : g == 1 ? v1 : g == 2 ? v2 : v3;
}

// ---- CSR build ------------------------------------------------------------

__global__ void count_kernel(const int* __restrict__ dst, int E, int* __restrict__ counts) {
    int e = blockIdx.x * blockDim.x + threadIdx.x;
    if (e < E) atomicAdd(&counts[dst[e]], 1);
}

__global__ void scan_pass1(const int* __restrict__ counts, int n, int* __restrict__ blockSums) {
    __shared__ int sh[256];
    int base = blockIdx.x * 2048;
    int tid = threadIdx.x;
    int s = 0;
#pragma unroll
    for (int j = 0; j < 8; ++j) {
        int idx = base + tid * 8 + j;
        if (idx < n) s += counts[idx];
    }
    sh[tid] = s;
    __syncthreads();
    for (int off = 128; off > 0; off >>= 1) {
        if (tid < off) sh[tid] += sh[tid + off];
        __syncthreads();
    }
    if (tid == 0) blockSums[blockIdx.x] = sh[0];
}

__global__ void scan_pass2(const int* __restrict__ blockSums, int nb, int* __restrict__ blockOffs) {
    if (threadIdx.x == 0 && blockIdx.x == 0) {
        int run = 0;
        for (int i = 0; i < nb; ++i) { blockOffs[i] = run; run += blockSums[i]; }
    }
}

__global__ void scan_pass3(const int* __restrict__ counts, int n,
                           const int* __restrict__ blockOffs,
                           const float* __restrict__ x,
                           int* __restrict__ row_ptr, int* __restrict__ cursor,
                           float* __restrict__ dinv, float* __restrict__ rdinv,
                           _Float16* __restrict__ xs) {
    __shared__ int sh[256];
    int base = blockIdx.x * 2048;
    int tid = threadIdx.x;
    int cnt[8];
    int local = 0;
#pragma unroll
    for (int j = 0; j < 8; ++j) {
        int idx = base + tid * 8 + j;
        cnt[j] = (idx < n) ? counts[idx] : 0;
        local += cnt[j];
    }
    sh[tid] = local;
    __syncthreads();
    for (int off = 1; off < 256; off <<= 1) {
        int v = (tid >= off) ? sh[tid - off] : 0;
        __syncthreads();
        sh[tid] += v;
        __syncthreads();
    }
    int run = blockOffs[blockIdx.x] + sh[tid] - local;
#pragma unroll
    for (int j = 0; j < 8; ++j) {
        int idx = base + tid * 8 + j;
        if (idx < n) {
            row_ptr[idx] = run;
            cursor[idx] = run;
            float dv = rsqrtf((float)(cnt[j] + 1));
            dinv[idx] = dv;
            rdinv[idx] = sqrtf((float)(cnt[j] + 1));
#pragma unroll
            for (int t = 0; t < 8; ++t) xs[idx * 8 + t] = (_Float16)(dv * x[idx * 8 + t]);
            run += cnt[j];
            if (idx == n - 1) row_ptr[n] = run;
        }
    }
}

// multi-pass range-filtered scatter: group blockIdx&7 handles a contiguous
// 1/8 dst range -> col_src/cursor writes are XCD-local, lines merge in L2.
__global__ void scatter_kernel(const int* __restrict__ src, const int* __restrict__ dst,
                               int E, int range,
                               int* __restrict__ cursor, int* __restrict__ col_src) {
    int grp = blockIdx.x & 7;
    int nlo = grp * range;
    int nhi = nlo + range;
    int nblk = gridDim.x >> 3;
    int c = blockIdx.x >> 3;
    int stride = nblk * blockDim.x;
    for (int e = c * blockDim.x + threadIdx.x; e < E; e += stride) {
        int d = dst[e];
        if (d >= nlo && d < nhi) {
            int pos = atomicAdd(&cursor[d], 1);
            col_src[pos] = src[e];
        }
    }
}

// ---- weight precompute: Ccomb/bcomb + attention-effective vectors ---------

__global__ void ccomb_kernel(const float* __restrict__ Wg, const float* __restrict__ bg,
                             const float* __restrict__ wc1, const float* __restrict__ bc1,
                             const float* __restrict__ att_src, const float* __restrict__ att_dst,
                             float* __restrict__ Ccomb, float* __restrict__ bcomb,
                             float* __restrict__ wse, float* __restrict__ wde) {
    int bid = blockIdx.x;   // 0..256
    int j = threadIdx.x;    // 64 threads
    if (bid < 256) {
        int h = bid >> 6, k = bid & 63;
        float s = 0.f;
        for (int c = 0; c < 64; ++c)
            s += Wg[k * 256 + h * 64 + c] * wc1[(h * 64 + c) * 64 + j];
        Ccomb[bid * 64 + j] = s;
    } else {
        float s = bc1[j];
        for (int i = 0; i < 256; ++i) s += bg[i] * wc1[i * 64 + j];
        bcomb[j] = s;
#pragma unroll
        for (int h = 0; h < 4; ++h) {
            float ss = 0.f, sd = 0.f;
            for (int c = 0; c < 64; ++c) {
                float w = Wg[j * 256 + h * 64 + c];
                ss += w * att_src[h * 64 + c];
                sd += w * att_dst[h * 64 + c];
            }
            wse[j * 4 + h] = ss;
            wde[j * 4 + h] = sd;
        }
    }
}

// ---- GCN layer 1: one edge per lane (16B half8 row) -----------------------

__global__ void gcn_layer1(const half8* __restrict__ xs8,
                           const float* __restrict__ W1, const float* __restrict__ b1,
                           const int* __restrict__ row_ptr, const int* __restrict__ col_src,
                           const float* __restrict__ dinv, int n,
                           _Float16* __restrict__ hs1) {
    int tid = threadIdx.x, lane = tid & 63, wid = tid >> 6;
    int node = blockIdx.x * 4 + wid;
    if (node >= n) return;
    int beg = row_ptr[node], end = row_ptr[node + 1];
    int deg = end - beg;
    float acc[8] = {0.f, 0.f, 0.f, 0.f, 0.f, 0.f, 0.f, 0.f};
    for (int base = 0; base < deg; base += 64) {
        int cs = col_src[min(beg + base + lane, end - 1)];
        half8 v = xs8[cs];
        if (base + lane < deg) {
#pragma unroll
            for (int c = 0; c < 8; ++c) acc[c] += (float)v[c];
        }
    }
#pragma unroll
    for (int c = 0; c < 8; ++c) acc[c] = red64(acc[c]);
    half8 sv = xs8[node];
    float di = dinv[node];
    float agg[8];
#pragma unroll
    for (int c = 0; c < 8; ++c) agg[c] = (acc[c] + (float)sv[c]) * di;
    float sum = b1[lane];
#pragma unroll
    for (int k = 0; k < 8; ++k) sum = fmaf(agg[k], W1[k * 64 + lane], sum);
    hs1[node * 64 + lane] = (_Float16)(di * fmaxf(sum, 0.f));
}

// ---- GCN layer 2/3: g=lane&7 edge slots, t=lane>>3 channel chunks ---------

template <bool LAST>
__global__ void gcn_layer64(const _Float16* __restrict__ hs_in,
                            const float* __restrict__ W, const float* __restrict__ b,
                            const int* __restrict__ row_ptr, const int* __restrict__ col_src,
                            const float* __restrict__ dinv, const float* __restrict__ rdinv,
                            const float* __restrict__ wse, const float* __restrict__ wde,
                            int n,
                            _Float16* __restrict__ hout,
                            float4* __restrict__ a_src4, float4* __restrict__ a_dst4) {
    __shared__ float agg_lds[4][64];
    int tid = threadIdx.x;
    int lane = tid & 63;
    int wid = tid >> 6;
    int t = lane >> 3, g = lane & 7;
    const half8* hs8 = (const half8*)hs_in;
    float wreg[64];
#pragma unroll
    for (int k = 0; k < 64; ++k) wreg[k] = W[k * 64 + lane];
    float bl = b[lane];
    float4 we, wd;
    if (LAST) {
        we = ((const float4*)wse)[lane];
        wd = ((const float4*)wde)[lane];
    }
    int nw = gridDim.x * 4;
    for (int node = blockIdx.x * 4 + wid; node < n; node += nw) {
        int beg = row_ptr[node], end = row_ptr[node + 1];
        int deg = end - beg;
        half8 sv = hs8[node * 8 + t];
        float ac[8];
#pragma unroll
        for (int c = 0; c < 8; ++c) ac[c] = (g == 0) ? (float)sv[c] : 0.f;
        for (int base = 0; base < deg; base += 64) {
            int cs = col_src[min(beg + base + lane, end - 1)];
            int lim = min(deg - base, 64);
            for (int chunk = 0; chunk < lim; chunk += 16) {
#pragma unroll
                for (int u = 0; u < 2; ++u) {
                    int eo = chunk + u * 8 + g;
                    int s = __shfl(cs, eo);
                    half8 v = hs8[s * 8 + t];
                    if (eo < lim) {
#pragma unroll
                        for (int c = 0; c < 8; ++c) ac[c] += (float)v[c];
                    }
                }
            }
        }
        float di = dinv[node];
#pragma unroll
        for (int c = 0; c < 8; ++c) ac[c] = red8(ac[c]) * di;
        if (g == 0) {
            *(float4*)&agg_lds[wid][t * 8]     = make_float4(ac[0], ac[1], ac[2], ac[3]);
            *(float4*)&agg_lds[wid][t * 8 + 4] = make_float4(ac[4], ac[5], ac[6], ac[7]);
        }
        __asm__ volatile("s_waitcnt lgkmcnt(0)" ::: "memory");
        float sum = bl;
#pragma unroll
        for (int k4 = 0; k4 < 16; ++k4) {
            float4 a4 = *(const float4*)&agg_lds[wid][k4 * 4];
            sum = fmaf(a4.x, wreg[k4 * 4 + 0], sum);
            sum = fmaf(a4.y, wreg[k4 * 4 + 1], sum);
            sum = fmaf(a4.z, wreg[k4 * 4 + 2], sum);
            sum = fmaf(a4.w, wreg[k4 * 4 + 3], sum);
        }
        float hprev = rdinv[node] * (float)hs_in[node * 64 + lane];
        float hv = hprev + fmaxf(sum, 0.f);
        if (!LAST) {
            hout[node * 64 + lane] = (_Float16)(di * hv);
        } else {
            hout[node * 64 + lane] = (_Float16)hv;
            float vs0 = red64(hv * we.x), vs1 = red64(hv * we.y);
            float vs2 = red64(hv * we.z), vs3 = red64(hv * we.w);
            float vd0 = red64(hv * wd.x), vd1 = red64(hv * wd.y);
            float vd2 = red64(hv * wd.z), vd3 = red64(hv * wd.w);
            if (lane == 0) {
                a_src4[node] = make_float4(vs0, vs1, vs2, vs3);
                a_dst4[node] = make_float4(vd0, vd1, vd2, vd3);
            }
        }
    }
}

// ---- GAT aggregate: writes fp16 agg rows ----------------------------------

__global__ void gat_agg(const _Float16* __restrict__ h3,
                        const float4* __restrict__ a_src4, const float4* __restrict__ a_dst4,
                        const int* __restrict__ row_ptr, const int* __restrict__ col_src,
                        int nbase, int ncount, _Float16* __restrict__ aggout) {
    int tid = threadIdx.x, lane = tid & 63, wid = tid >> 6;
    int li = blockIdx.x * 4 + wid;
    if (li >= ncount) return;
    int node = nbase + li;
    int t = lane >> 3, g = lane & 7;
    const half8* h38 = (const half8*)h3;

    float4 ad = a_dst4[node];
    float4 asf = a_src4[node];
    half8 hself = h38[node * 8 + t];
    float A[4][8], dh[4];
    {
        float w0 = __expf(leaky02(asf.x + ad.x));
        float w1 = __expf(leaky02(asf.y + ad.y));
        float w2 = __expf(leaky02(asf.z + ad.z));
        float w3 = __expf(leaky02(asf.w + ad.w));
        float m0 = (g == 0) ? 1.f : 0.f;
        dh[0] = m0 * w0; dh[1] = m0 * w1; dh[2] = m0 * w2; dh[3] = m0 * w3;
#pragma unroll
        for (int c = 0; c < 8; ++c) {
            float hvc = (float)hself[c];
            A[0][c] = dh[0] * hvc;
            A[1][c] = dh[1] * hvc;
            A[2][c] = dh[2] * hvc;
            A[3][c] = dh[3] * hvc;
        }
    }
    int beg = row_ptr[node], end = row_ptr[node + 1];
    int deg = end - beg;
    for (int base = 0; base < deg; base += 64) {
        int cs = col_src[min(beg + base + lane, end - 1)];
        int lim = min(deg - base, 64);
        for (int chunk = 0; chunk < lim; chunk += 16) {
#pragma unroll
            for (int u = 0; u < 2; ++u) {
                int eo = chunk + u * 8 + g;
                int s = __shfl(cs, eo);
                float4 as = a_src4[s];
                half8 hv = h38[s * 8 + t];
                float valid = (eo < lim) ? 1.f : 0.f;
                float w0 = valid * __expf(leaky02(as.x + ad.x));
                float w1 = valid * __expf(leaky02(as.y + ad.y));
                float w2 = valid * __expf(leaky02(as.z + ad.z));
                float w3 = valid * __expf(leaky02(as.w + ad.w));
#pragma unroll
                for (int c = 0; c < 8; ++c) {
                    float hvc = (float)hv[c];
                    A[0][c] = fmaf(w0, hvc, A[0][c]);
                    A[1][c] = fmaf(w1, hvc, A[1][c]);
                    A[2][c] = fmaf(w2, hvc, A[2][c]);
                    A[3][c] = fmaf(w3, hvc, A[3][c]);
                }
                dh[0] += w0; dh[1] += w1; dh[2] += w2; dh[3] += w3;
            }
        }
    }
#pragma unroll
    for (int h = 0; h < 4; ++h) {
#pragma unroll
        for (int c = 0; c < 8; ++c) A[h][c] = red8(A[h][c]);
        dh[h] = red8(dh[h]);
    }
    float r0 = 1.f / (dh[0] + 1e-16f);
    float r1 = 1.f / (dh[1] + 1e-16f);
    float r2 = 1.f / (dh[2] + 1e-16f);
    float r3 = 1.f / (dh[3] + 1e-16f);
    if (g < 4) {
        float r = sel4(g, r0, r1, r2, r3);
        half8 hv;
#pragma unroll
        for (int c = 0; c < 8; ++c)
            hv[c] = (_Float16)(sel4(g, A[0][c], A[1][c], A[2][c], A[3][c]) * r);
        *(half8*)(aggout + (size_t)li * 256 + g * 64 + t * 8) = hv;
    }
}

// ---- MLP: Ccomb rows in VGPRs (4-wave split), fp16 agg scalar loads -------

__global__ __launch_bounds__(256) void mlp_kernel(
        const _Float16* __restrict__ agg,
        const float* __restrict__ Ccomb, const float* __restrict__ bcomb,
        const float* __restrict__ wc2, const float* __restrict__ bc2,
        int nbase, int ncount, float* __restrict__ out) {
    __shared__ float part[4][4][64];   // [node-in-chunk][wave][lane]
    int tid = threadIdx.x;
    int lane = tid & 63;
    int w = __builtin_amdgcn_readfirstlane(tid >> 6);
    float creg[64];
#pragma unroll
    for (int i = 0; i < 64; ++i) creg[i] = Ccomb[(w * 64 + i) * 64 + lane];
    float bz = bcomb[lane];
    float w20 = wc2[lane * 3 + 0], w21 = wc2[lane * 3 + 1], w22 = wc2[lane * 3 + 2];
    float bb0 = bc2[0], bb1 = bc2[1], bb2 = bc2[2];
    int nchunks = (ncount + 3) >> 2;
    for (int ch = blockIdx.x; ch < nchunks; ch += gridDim.x) {
        int base = ch * 4;
#pragma unroll
        for (int j = 0; j < 4; ++j) {
            int li = min(base + j, ncount - 1);
            const half2v* a2 = (const half2v*)(agg + (size_t)li * 256 + w * 64);
            float p = 0.f;
#pragma unroll
            for (int i = 0; i < 32; ++i) {
                half2v hv = a2[i];
                p = fmaf((float)hv[0], creg[2 * i], p);
                p = fmaf((float)hv[1], creg[2 * i + 1], p);
            }
            part[j][w][lane] = p;
        }
        __syncthreads();
        int li = base + w;
        if (li < ncount) {
            float z = bz + part[w][0][lane] + part[w][1][lane]
                         + part[w][2][lane] + part[w][3][lane];
            z = fmaxf(z, 0.f);
            float p0 = red64(z * w20);
            float p1 = red64(z * w21);
            float p2 = red64(z * w22);
            if (lane == 0) {
                float e0 = p0 + bb0, e1 = p1 + bb1, e2 = p2 + bb2;
                float mx = fmaxf(e0, fmaxf(e1, e2));
                float lse = mx + logf(expf(e0 - mx) + expf(e1 - mx) + expf(e2 - mx));
                int nn = nbase + li;
                out[nn * 3 + 0] = e0 - lse;
                out[nn * 3 + 1] = e1 - lse;
                out[nn * 3 + 2] = e2 - lse;
            }
        }
        __syncthreads();
    }
}

// ---------------------------------------------------------------------------

extern "C" void kernel_launch(void* const* d_in, const int* in_sizes, int n_in,
                              void* d_out, int out_size, void* d_ws, size_t ws_size,
                              hipStream_t stream) {
    const float* x       = (const float*)d_in[0];
    const int*   ei      = (const int*)d_in[1];
    const float* w1      = (const float*)d_in[2];
    const float* b1      = (const float*)d_in[3];
    const float* w2      = (const float*)d_in[4];
    const float* b2      = (const float*)d_in[5];
    const float* w3      = (const float*)d_in[6];
    const float* b3      = (const float*)d_in[7];
    const float* wg      = (const float*)d_in[8];
    const float* bg      = (const float*)d_in[9];
    const float* att_s   = (const float*)d_in[10];
    const float* att_d   = (const float*)d_in[11];
    const float* wc1     = (const float*)d_in[12];
    const float* bc1     = (const float*)d_in[13];
    const float* wc2     = (const float*)d_in[14];
    const float* bc2     = (const float*)d_in[15];
    float* out = (float*)d_out;

    const int N = in_sizes[0] / 8;
    const int E = in_sizes[1] / 2;
    const int* srcv = ei;
    const int* dstv = ei + E;

    char* ws = (char*)d_ws;
    size_t off = 0;
    auto alloc = [&](size_t bytes) -> char* {
        char* p = ws + off;
        off += (bytes + 255) & ~(size_t)255;
        return p;
    };
    int*      counts    = (int*)alloc((size_t)N * 4);
    int*      row_ptr   = (int*)alloc((size_t)(N + 1) * 4);
    int*      cursor    = (int*)alloc((size_t)N * 4);
    int*      col_src   = (int*)alloc((size_t)E * 4);
    int*      blockSums = (int*)alloc(4096 * 4);
    int*      blockOffs = (int*)alloc(4096 * 4);
    float*    dinv      = (float*)alloc((size_t)N * 4);
    float*    rdinv     = (float*)alloc((size_t)N * 4);
    _Float16* xs        = (_Float16*)alloc((size_t)N * 8 * 2);
    float*    a_src     = (float*)alloc((size_t)N * 16);
    float*    a_dst     = (float*)alloc((size_t)N * 16);
    float*    wse       = (float*)alloc(256 * 4);
    float*    wde       = (float*)alloc(256 * 4);
    float*    Ccomb     = (float*)alloc(256 * 64 * 4);
    float*    bcomb     = (float*)alloc(64 * 4);
    _Float16* bufA      = (_Float16*)alloc((size_t)N * 64 * 2);  // hs1, later h3
    _Float16* bufB      = (_Float16*)alloc((size_t)N * 64 * 2);  // hs2
    const int S = (N + 3) / 4;                                   // stripe size
    _Float16* aggbuf    = (_Float16*)alloc((size_t)S * 256 * 2);
    _Float16* hs1 = bufA;
    _Float16* hs2 = bufB;
    _Float16* h3  = bufA;   // hs1 dead once layer3 runs
    (void)ws_size; (void)n_in; (void)out_size;

    hipMemsetAsync(counts, 0, (size_t)N * 4, stream);

    const int TPB = 256;
    int gridE = (E + TPB - 1) / TPB;
    count_kernel<<<gridE, TPB, 0, stream>>>(dstv, E, counts);

    int NB = (N + 2047) / 2048;
    scan_pass1<<<NB, TPB, 0, stream>>>(counts, N, blockSums);
    scan_pass2<<<1, 64, 0, stream>>>(blockSums, NB, blockOffs);
    scan_pass3<<<NB, TPB, 0, stream>>>(counts, N, blockOffs, x,
                                       row_ptr, cursor, dinv, rdinv, xs);
    int range = (N + 7) / 8;
    scatter_kernel<<<1024, TPB, 0, stream>>>(srcv, dstv, E, range, cursor, col_src);

    ccomb_kernel<<<257, 64, 0, stream>>>(wg, bg, wc1, bc1, att_s, att_d,
                                         Ccomb, bcomb, wse, wde);

    int gridN = (N + 3) / 4;
    gcn_layer1<<<gridN, TPB, 0, stream>>>((const half8*)xs, w1, b1, row_ptr, col_src,
                                          dinv, N, hs1);
    const int G64 = 1024;   // grid-stride: ~24 nodes/wave, amortizes W VGPR load
    gcn_layer64<false><<<G64, TPB, 0, stream>>>(hs1, w2, b2, row_ptr, col_src,
                                                dinv, rdinv, wse, wde, N, hs2,
                                                nullptr, nullptr);
    gcn_layer64<true><<<G64, TPB, 0, stream>>>(hs2, w3, b3, row_ptr, col_src,
                                               dinv, rdinv, wse, wde, N, h3,
                                               (float4*)a_src, (float4*)a_dst);

    // GAT + MLP in 4 stripes reusing the agg slab
    for (int s = 0; s < 4; ++s) {
        int nbase = s * S;
        if (nbase >= N) break;
        int ncount = min(S, N - nbase);
        int gridA = (ncount + 3) / 4;   // 1 node per wave
        gat_agg<<<gridA, TPB, 0, stream>>>(h3, (const float4*)a_src, (const float4*)a_dst,
                                           row_ptr, col_src, nbase, ncount, aggbuf);
        mlp_kernel<<<512, TPB, 0, stream>>>(aggbuf, Ccomb, bcomb, wc2, bc2,
                                            nbase, ncount, out);
    }
}

// Round 10
// 643.227 us; speedup vs baseline: 6.9404x; 1.1033x over previous
//
#include <hip/hip_runtime.h>
#include <math.h>

// ---------------------------------------------------------------------------
// SpatialGNN: 3x GCN (residual) + 4-head GAT + MLP + log_softmax
// N=100000, E=1600000, IN=8, HID=64, HEADS=4, OUT=3
//
// R10 changes vs R9:
//  - gcn_layer64 grid 1024->2048: occupancy was grid-capped at 39%; the
//    kernel is at its structural beyond-L2 byte floor (~8x working set), so
//    the lever is outstanding-miss parallelism, not bytes.
//  - count_kernel XCD-range-filtered (same fix as scatter): counter cache
//    lines stay in one XCD's L2 instead of bouncing.
//  - Single full-N gat_agg + mlp (no 4-stripe loop): fp16 aggbuf 51.2MB,
//    total ws ~90MB (<= R4's proven 92MB).
//  - gcn_layer64: hprev taken from already-loaded sv[g].
// ---------------------------------------------------------------------------

typedef _Float16 half8 __attribute__((ext_vector_type(8)));
typedef _Float16 half2v __attribute__((ext_vector_type(2)));

__device__ __forceinline__ float leaky02(float v) { return v > 0.f ? v : 0.2f * v; }

// ---- cross-lane reduction helpers (DPP/swizzle; minimize DS-pipe ops) -----

template <int CTRL>
__device__ __forceinline__ float dpp_add(float v) {
    int iv = __builtin_bit_cast(int, v);
    int r = __builtin_amdgcn_update_dpp(iv, iv, CTRL, 0xF, 0xF, false);
    return v + __builtin_bit_cast(float, r);
}
template <int OFF>
__device__ __forceinline__ float swz_add(float v) {
    int r = __builtin_amdgcn_ds_swizzle(__builtin_bit_cast(int, v), OFF);
    return v + __builtin_bit_cast(float, r);
}
__device__ __forceinline__ float red8(float v) {
    v = dpp_add<0xB1>(v);     // xor1
    v = dpp_add<0x4E>(v);     // xor2
    v = swz_add<0x101F>(v);   // xor4
    return v;
}
__device__ __forceinline__ float red64(float v) {
    v = dpp_add<0xB1>(v);
    v = dpp_add<0x4E>(v);
    v = swz_add<0x101F>(v);
    v = dpp_add<0x128>(v);    // xor8: row_ror:8
    v = swz_add<0x401F>(v);   // xor16
    v = v + __shfl_xor(v, 32);
    return v;
}
__device__ __forceinline__ float sel4(int g, float v0, float v1, float v2, float v3) {
    return g == 0 ? v0 : g == 1 ? v1 : g == 2 ? v2 : v3;
}

// ---- CSR build ------------------------------------------------------------

// XCD-range-filtered count: group blockIdx&7 counts only its dst range.
__global__ void count_kernel(const int* __restrict__ dst, int E, int range,
                             int* __restrict__ counts) {
    int grp = blockIdx.x & 7;
    int nlo = grp * range;
    int nhi = nlo + range;
    int nblk = gridDim.x >> 3;
    int c = blockIdx.x >> 3;
    int stride = nblk * blockDim.x;
    for (int e = c * blockDim.x + threadIdx.x; e < E; e += stride) {
        int d = dst[e];
        if (d >= nlo && d < nhi) atomicAdd(&counts[d], 1);
    }
}

__global__ void scan_pass1(const int* __restrict__ counts, int n, int* __restrict__ blockSums) {
    __shared__ int sh[256];
    int base = blockIdx.x * 2048;
    int tid = threadIdx.x;
    int s = 0;
#pragma unroll
    for (int j = 0; j < 8; ++j) {
        int idx = base + tid * 8 + j;
        if (idx < n) s += counts[idx];
    }
    sh[tid] = s;
    __syncthreads();
    for (int off = 128; off > 0; off >>= 1) {
        if (tid < off) sh[tid] += sh[tid + off];
        __syncthreads();
    }
    if (tid == 0) blockSums[blockIdx.x] = sh[0];
}

__global__ void scan_pass2(const int* __restrict__ blockSums, int nb, int* __restrict__ blockOffs) {
    if (threadIdx.x == 0 && blockIdx.x == 0) {
        int run = 0;
        for (int i = 0; i < nb; ++i) { blockOffs[i] = run; run += blockSums[i]; }
    }
}

__global__ void scan_pass3(const int* __restrict__ counts, int n,
                           const int* __restrict__ blockOffs,
                           const float* __restrict__ x,
                           int* __restrict__ row_ptr, int* __restrict__ cursor,
                           float* __restrict__ dinv, float* __restrict__ rdinv,
                           _Float16* __restrict__ xs) {
    __shared__ int sh[256];
    int base = blockIdx.x * 2048;
    int tid = threadIdx.x;
    int cnt[8];
    int local = 0;
#pragma unroll
    for (int j = 0; j < 8; ++j) {
        int idx = base + tid * 8 + j;
        cnt[j] = (idx < n) ? counts[idx] : 0;
        local += cnt[j];
    }
    sh[tid] = local;
    __syncthreads();
    for (int off = 1; off < 256; off <<= 1) {
        int v = (tid >= off) ? sh[tid - off] : 0;
        __syncthreads();
        sh[tid] += v;
        __syncthreads();
    }
    int run = blockOffs[blockIdx.x] + sh[tid] - local;
#pragma unroll
    for (int j = 0; j < 8; ++j) {
        int idx = base + tid * 8 + j;
        if (idx < n) {
            row_ptr[idx] = run;
            cursor[idx] = run;
            float dv = rsqrtf((float)(cnt[j] + 1));
            dinv[idx] = dv;
            rdinv[idx] = sqrtf((float)(cnt[j] + 1));
#pragma unroll
            for (int t = 0; t < 8; ++t) xs[idx * 8 + t] = (_Float16)(dv * x[idx * 8 + t]);
            run += cnt[j];
            if (idx == n - 1) row_ptr[n] = run;
        }
    }
}

// XCD-range-filtered scatter (R9, kept): col_src/cursor writes stay XCD-local.
__global__ void scatter_kernel(const int* __restrict__ src, const int* __restrict__ dst,
                               int E, int range,
                               int* __restrict__ cursor, int* __restrict__ col_src) {
    int grp = blockIdx.x & 7;
    int nlo = grp * range;
    int nhi = nlo + range;
    int nblk = gridDim.x >> 3;
    int c = blockIdx.x >> 3;
    int stride = nblk * blockDim.x;
    for (int e = c * blockDim.x + threadIdx.x; e < E; e += stride) {
        int d = dst[e];
        if (d >= nlo && d < nhi) {
            int pos = atomicAdd(&cursor[d], 1);
            col_src[pos] = src[e];
        }
    }
}

// ---- weight precompute: Ccomb/bcomb + attention-effective vectors ---------

__global__ void ccomb_kernel(const float* __restrict__ Wg, const float* __restrict__ bg,
                             const float* __restrict__ wc1, const float* __restrict__ bc1,
                             const float* __restrict__ att_src, const float* __restrict__ att_dst,
                             float* __restrict__ Ccomb, float* __restrict__ bcomb,
                             float* __restrict__ wse, float* __restrict__ wde) {
    int bid = blockIdx.x;   // 0..256
    int j = threadIdx.x;    // 64 threads
    if (bid < 256) {
        int h = bid >> 6, k = bid & 63;
        float s = 0.f;
        for (int c = 0; c < 64; ++c)
            s += Wg[k * 256 + h * 64 + c] * wc1[(h * 64 + c) * 64 + j];
        Ccomb[bid * 64 + j] = s;
    } else {
        float s = bc1[j];
        for (int i = 0; i < 256; ++i) s += bg[i] * wc1[i * 64 + j];
        bcomb[j] = s;
#pragma unroll
        for (int h = 0; h < 4; ++h) {
            float ss = 0.f, sd = 0.f;
            for (int c = 0; c < 64; ++c) {
                float w = Wg[j * 256 + h * 64 + c];
                ss += w * att_src[h * 64 + c];
                sd += w * att_dst[h * 64 + c];
            }
            wse[j * 4 + h] = ss;
            wde[j * 4 + h] = sd;
        }
    }
}

// ---- GCN layer 1: one edge per lane (16B half8 row) -----------------------

__global__ void gcn_layer1(const half8* __restrict__ xs8,
                           const float* __restrict__ W1, const float* __restrict__ b1,
                           const int* __restrict__ row_ptr, const int* __restrict__ col_src,
                           const float* __restrict__ dinv, int n,
                           _Float16* __restrict__ hs1) {
    int tid = threadIdx.x, lane = tid & 63, wid = tid >> 6;
    int node = blockIdx.x * 4 + wid;
    if (node >= n) return;
    int beg = row_ptr[node], end = row_ptr[node + 1];
    int deg = end - beg;
    float acc[8] = {0.f, 0.f, 0.f, 0.f, 0.f, 0.f, 0.f, 0.f};
    for (int base = 0; base < deg; base += 64) {
        int cs = col_src[min(beg + base + lane, end - 1)];
        half8 v = xs8[cs];
        if (base + lane < deg) {
#pragma unroll
            for (int c = 0; c < 8; ++c) acc[c] += (float)v[c];
        }
    }
#pragma unroll
    for (int c = 0; c < 8; ++c) acc[c] = red64(acc[c]);
    half8 sv = xs8[node];
    float di = dinv[node];
    float agg[8];
#pragma unroll
    for (int c = 0; c < 8; ++c) agg[c] = (acc[c] + (float)sv[c]) * di;
    float sum = b1[lane];
#pragma unroll
    for (int k = 0; k < 8; ++k) sum = fmaf(agg[k], W1[k * 64 + lane], sum);
    hs1[node * 64 + lane] = (_Float16)(di * fmaxf(sum, 0.f));
}

// ---- GCN layer 2/3: g=lane&7 edge slots, t=lane>>3 channel chunks ---------

template <bool LAST>
__global__ void gcn_layer64(const _Float16* __restrict__ hs_in,
                            const float* __restrict__ W, const float* __restrict__ b,
                            const int* __restrict__ row_ptr, const int* __restrict__ col_src,
                            const float* __restrict__ dinv, const float* __restrict__ rdinv,
                            const float* __restrict__ wse, const float* __restrict__ wde,
                            int n,
                            _Float16* __restrict__ hout,
                            float4* __restrict__ a_src4, float4* __restrict__ a_dst4) {
    __shared__ float agg_lds[4][64];
    int tid = threadIdx.x;
    int lane = tid & 63;
    int wid = tid >> 6;
    int t = lane >> 3, g = lane & 7;
    const half8* hs8 = (const half8*)hs_in;
    float wreg[64];
#pragma unroll
    for (int k = 0; k < 64; ++k) wreg[k] = W[k * 64 + lane];
    float bl = b[lane];
    float4 we, wd;
    if (LAST) {
        we = ((const float4*)wse)[lane];
        wd = ((const float4*)wde)[lane];
    }
    int nw = gridDim.x * 4;
    for (int node = blockIdx.x * 4 + wid; node < n; node += nw) {
        int beg = row_ptr[node], end = row_ptr[node + 1];
        int deg = end - beg;
        half8 sv = hs8[node * 8 + t];
        float ac[8];
#pragma unroll
        for (int c = 0; c < 8; ++c) ac[c] = (g == 0) ? (float)sv[c] : 0.f;
        for (int base = 0; base < deg; base += 64) {
            int cs = col_src[min(beg + base + lane, end - 1)];
            int lim = min(deg - base, 64);
            for (int chunk = 0; chunk < lim; chunk += 16) {
#pragma unroll
                for (int u = 0; u < 2; ++u) {
                    int eo = chunk + u * 8 + g;
                    int s = __shfl(cs, eo);
                    half8 v = hs8[s * 8 + t];
                    if (eo < lim) {
#pragma unroll
                        for (int c = 0; c < 8; ++c) ac[c] += (float)v[c];
                    }
                }
            }
        }
        float di = dinv[node];
#pragma unroll
        for (int c = 0; c < 8; ++c) ac[c] = red8(ac[c]) * di;
        if (g == 0) {
            *(float4*)&agg_lds[wid][t * 8]     = make_float4(ac[0], ac[1], ac[2], ac[3]);
            *(float4*)&agg_lds[wid][t * 8 + 4] = make_float4(ac[4], ac[5], ac[6], ac[7]);
        }
        __asm__ volatile("s_waitcnt lgkmcnt(0)" ::: "memory");
        float sum = bl;
#pragma unroll
        for (int k4 = 0; k4 < 16; ++k4) {
            float4 a4 = *(const float4*)&agg_lds[wid][k4 * 4];
            sum = fmaf(a4.x, wreg[k4 * 4 + 0], sum);
            sum = fmaf(a4.y, wreg[k4 * 4 + 1], sum);
            sum = fmaf(a4.z, wreg[k4 * 4 + 2], sum);
            sum = fmaf(a4.w, wreg[k4 * 4 + 3], sum);
        }
        float hprev = rdinv[node] * (float)sv[g];   // sv[g] == hs_in[node*64+lane]
        float hv = hprev + fmaxf(sum, 0.f);
        if (!LAST) {
            hout[node * 64 + lane] = (_Float16)(di * hv);
        } else {
            hout[node * 64 + lane] = (_Float16)hv;
            float vs0 = red64(hv * we.x), vs1 = red64(hv * we.y);
            float vs2 = red64(hv * we.z), vs3 = red64(hv * we.w);
            float vd0 = red64(hv * wd.x), vd1 = red64(hv * wd.y);
            float vd2 = red64(hv * wd.z), vd3 = red64(hv * wd.w);
            if (lane == 0) {
                a_src4[node] = make_float4(vs0, vs1, vs2, vs3);
                a_dst4[node] = make_float4(vd0, vd1, vd2, vd3);
            }
        }
    }
}

// ---- GAT aggregate: writes fp16 agg rows (full N, single launch) ----------

__global__ void gat_agg(const _Float16* __restrict__ h3,
                        const float4* __restrict__ a_src4, const float4* __restrict__ a_dst4,
                        const int* __restrict__ row_ptr, const int* __restrict__ col_src,
                        int n, _Float16* __restrict__ aggout) {
    int tid = threadIdx.x, lane = tid & 63, wid = tid >> 6;
    int node = blockIdx.x * 4 + wid;
    if (node >= n) return;
    int t = lane >> 3, g = lane & 7;
    const half8* h38 = (const half8*)h3;

    float4 ad = a_dst4[node];
    float4 asf = a_src4[node];
    half8 hself = h38[node * 8 + t];
    float A[4][8], dh[4];
    {
        float w0 = __expf(leaky02(asf.x + ad.x));
        float w1 = __expf(leaky02(asf.y + ad.y));
        float w2 = __expf(leaky02(asf.z + ad.z));
        float w3 = __expf(leaky02(asf.w + ad.w));
        float m0 = (g == 0) ? 1.f : 0.f;
        dh[0] = m0 * w0; dh[1] = m0 * w1; dh[2] = m0 * w2; dh[3] = m0 * w3;
#pragma unroll
        for (int c = 0; c < 8; ++c) {
            float hvc = (float)hself[c];
            A[0][c] = dh[0] * hvc;
            A[1][c] = dh[1] * hvc;
            A[2][c] = dh[2] * hvc;
            A[3][c] = dh[3] * hvc;
        }
    }
    int beg = row_ptr[node], end = row_ptr[node + 1];
    int deg = end - beg;
    for (int base = 0; base < deg; base += 64) {
        int cs = col_src[min(beg + base + lane, end - 1)];
        int lim = min(deg - base, 64);
        for (int chunk = 0; chunk < lim; chunk += 16) {
#pragma unroll
            for (int u = 0; u < 2; ++u) {
                int eo = chunk + u * 8 + g;
                int s = __shfl(cs, eo);
                float4 as = a_src4[s];
                half8 hv = h38[s * 8 + t];
                float valid = (eo < lim) ? 1.f : 0.f;
                float w0 = valid * __expf(leaky02(as.x + ad.x));
                float w1 = valid * __expf(leaky02(as.y + ad.y));
                float w2 = valid * __expf(leaky02(as.z + ad.z));
                float w3 = valid * __expf(leaky02(as.w + ad.w));
#pragma unroll
                for (int c = 0; c < 8; ++c) {
                    float hvc = (float)hv[c];
                    A[0][c] = fmaf(w0, hvc, A[0][c]);
                    A[1][c] = fmaf(w1, hvc, A[1][c]);
                    A[2][c] = fmaf(w2, hvc, A[2][c]);
                    A[3][c] = fmaf(w3, hvc, A[3][c]);
                }
                dh[0] += w0; dh[1] += w1; dh[2] += w2; dh[3] += w3;
            }
        }
    }
#pragma unroll
    for (int h = 0; h < 4; ++h) {
#pragma unroll
        for (int c = 0; c < 8; ++c) A[h][c] = red8(A[h][c]);
        dh[h] = red8(dh[h]);
    }
    float r0 = 1.f / (dh[0] + 1e-16f);
    float r1 = 1.f / (dh[1] + 1e-16f);
    float r2 = 1.f / (dh[2] + 1e-16f);
    float r3 = 1.f / (dh[3] + 1e-16f);
    if (g < 4) {
        float r = sel4(g, r0, r1, r2, r3);
        half8 hv;
#pragma unroll
        for (int c = 0; c < 8; ++c)
            hv[c] = (_Float16)(sel4(g, A[0][c], A[1][c], A[2][c], A[3][c]) * r);
        *(half8*)(aggout + (size_t)node * 256 + g * 64 + t * 8) = hv;
    }
}

// ---- MLP: Ccomb rows in VGPRs (4-wave split), fp16 agg scalar loads -------

__global__ __launch_bounds__(256) void mlp_kernel(
        const _Float16* __restrict__ agg,
        const float* __restrict__ Ccomb, const float* __restrict__ bcomb,
        const float* __restrict__ wc2, const float* __restrict__ bc2,
        int n, float* __restrict__ out) {
    __shared__ float part[4][4][64];   // [node-in-chunk][wave][lane]
    int tid = threadIdx.x;
    int lane = tid & 63;
    int w = __builtin_amdgcn_readfirstlane(tid >> 6);
    float creg[64];
#pragma unroll
    for (int i = 0; i < 64; ++i) creg[i] = Ccomb[(w * 64 + i) * 64 + lane];
    float bz = bcomb[lane];
    float w20 = wc2[lane * 3 + 0], w21 = wc2[lane * 3 + 1], w22 = wc2[lane * 3 + 2];
    float bb0 = bc2[0], bb1 = bc2[1], bb2 = bc2[2];
    int nchunks = (n + 3) >> 2;
    for (int ch = blockIdx.x; ch < nchunks; ch += gridDim.x) {
        int base = ch * 4;
#pragma unroll
        for (int j = 0; j < 4; ++j) {
            int li = min(base + j, n - 1);
            const half2v* a2 = (const half2v*)(agg + (size_t)li * 256 + w * 64);
            float p = 0.f;
#pragma unroll
            for (int i = 0; i < 32; ++i) {
                half2v hv = a2[i];
                p = fmaf((float)hv[0], creg[2 * i], p);
                p = fmaf((float)hv[1], creg[2 * i + 1], p);
            }
            part[j][w][lane] = p;
        }
        __syncthreads();
        int li = base + w;
        if (li < n) {
            float z = bz + part[w][0][lane] + part[w][1][lane]
                         + part[w][2][lane] + part[w][3][lane];
            z = fmaxf(z, 0.f);
            float p0 = red64(z * w20);
            float p1 = red64(z * w21);
            float p2 = red64(z * w22);
            if (lane == 0) {
                float e0 = p0 + bb0, e1 = p1 + bb1, e2 = p2 + bb2;
                float mx = fmaxf(e0, fmaxf(e1, e2));
                float lse = mx + logf(expf(e0 - mx) + expf(e1 - mx) + expf(e2 - mx));
                out[li * 3 + 0] = e0 - lse;
                out[li * 3 + 1] = e1 - lse;
                out[li * 3 + 2] = e2 - lse;
            }
        }
        __syncthreads();
    }
}

// ---------------------------------------------------------------------------

extern "C" void kernel_launch(void* const* d_in, const int* in_sizes, int n_in,
                              void* d_out, int out_size, void* d_ws, size_t ws_size,
                              hipStream_t stream) {
    const float* x       = (const float*)d_in[0];
    const int*   ei      = (const int*)d_in[1];
    const float* w1      = (const float*)d_in[2];
    const float* b1      = (const float*)d_in[3];
    const float* w2      = (const float*)d_in[4];
    const float* b2      = (const float*)d_in[5];
    const float* w3      = (const float*)d_in[6];
    const float* b3      = (const float*)d_in[7];
    const float* wg      = (const float*)d_in[8];
    const float* bg      = (const float*)d_in[9];
    const float* att_s   = (const float*)d_in[10];
    const float* att_d   = (const float*)d_in[11];
    const float* wc1     = (const float*)d_in[12];
    const float* bc1     = (const float*)d_in[13];
    const float* wc2     = (const float*)d_in[14];
    const float* bc2     = (const float*)d_in[15];
    float* out = (float*)d_out;

    const int N = in_sizes[0] / 8;
    const int E = in_sizes[1] / 2;
    const int* srcv = ei;
    const int* dstv = ei + E;

    char* ws = (char*)d_ws;
    size_t off = 0;
    auto alloc = [&](size_t bytes) -> char* {
        char* p = ws + off;
        off += (bytes + 255) & ~(size_t)255;
        return p;
    };
    int*      counts    = (int*)alloc((size_t)N * 4);
    int*      row_ptr   = (int*)alloc((size_t)(N + 1) * 4);
    int*      cursor    = (int*)alloc((size_t)N * 4);
    int*      col_src   = (int*)alloc((size_t)E * 4);
    int*      blockSums = (int*)alloc(4096 * 4);
    int*      blockOffs = (int*)alloc(4096 * 4);
    float*    dinv      = (float*)alloc((size_t)N * 4);
    float*    rdinv     = (float*)alloc((size_t)N * 4);
    _Float16* xs        = (_Float16*)alloc((size_t)N * 8 * 2);
    float*    a_src     = (float*)alloc((size_t)N * 16);
    float*    a_dst     = (float*)alloc((size_t)N * 16);
    float*    wse       = (float*)alloc(256 * 4);
    float*    wde       = (float*)alloc(256 * 4);
    float*    Ccomb     = (float*)alloc(256 * 64 * 4);
    float*    bcomb     = (float*)alloc(64 * 4);
    _Float16* bufA      = (_Float16*)alloc((size_t)N * 64 * 2);  // hs1, later h3
    _Float16* bufB      = (_Float16*)alloc((size_t)N * 64 * 2);  // hs2
    _Float16* aggbuf    = (_Float16*)alloc((size_t)N * 256 * 2); // 51.2MB fp16
    _Float16* hs1 = bufA;
    _Float16* hs2 = bufB;
    _Float16* h3  = bufA;   // hs1 dead once layer3 runs
    (void)ws_size; (void)n_in; (void)out_size;

    hipMemsetAsync(counts, 0, (size_t)N * 4, stream);

    const int TPB = 256;
    int range = (N + 7) / 8;
    count_kernel<<<1024, TPB, 0, stream>>>(dstv, E, range, counts);

    int NB = (N + 2047) / 2048;
    scan_pass1<<<NB, TPB, 0, stream>>>(counts, N, blockSums);
    scan_pass2<<<1, 64, 0, stream>>>(blockSums, NB, blockOffs);
    scan_pass3<<<NB, TPB, 0, stream>>>(counts, N, blockOffs, x,
                                       row_ptr, cursor, dinv, rdinv, xs);
    scatter_kernel<<<2048, TPB, 0, stream>>>(srcv, dstv, E, range, cursor, col_src);

    ccomb_kernel<<<257, 64, 0, stream>>>(wg, bg, wc1, bc1, att_s, att_d,
                                         Ccomb, bcomb, wse, wde);

    int gridN = (N + 3) / 4;
    gcn_layer1<<<gridN, TPB, 0, stream>>>((const half8*)xs, w1, b1, row_ptr, col_src,
                                          dinv, N, hs1);
    const int G64 = 2048;   // 8 blocks/CU: lift grid-capped occupancy (was 39%)
    gcn_layer64<false><<<G64, TPB, 0, stream>>>(hs1, w2, b2, row_ptr, col_src,
                                                dinv, rdinv, wse, wde, N, hs2,
                                                nullptr, nullptr);
    gcn_layer64<true><<<G64, TPB, 0, stream>>>(hs2, w3, b3, row_ptr, col_src,
                                               dinv, rdinv, wse, wde, N, h3,
                                               (float4*)a_src, (float4*)a_dst);

    gat_agg<<<gridN, TPB, 0, stream>>>(h3, (const float4*)a_src, (const float4*)a_dst,
                                       row_ptr, col_src, N, aggbuf);
    mlp_kernel<<<1024, TPB, 0, stream>>>(aggbuf, Ccomb, bcomb, wc2, bc2, N, out);
}